// Round 9
// baseline (24.322 us; speedup 1.0000x reference)
//
#include <hip/hip_runtime.h>
#include <math.h>

// Problem constants: B=1024, IN_DIM=4096, OUT_DIM=4096, FAN_IN=8
#define BDIM 1024
#define IN_DIM 4096
#define OUT_DIM 4096
#define FAN_IN 8
#define NT 1024
#define OPT (OUT_DIM / NT)      // 4 outputs per thread
#define PAIRS (IN_DIM / 2)      // 2048 float2 column-pairs per row
#define STG (PAIRS / NT)        // 2 staging iterations per tile

#define LOG2E 1.442695040888963f
#define LN2   0.6931471805599453f

// clang-native vector type: accepted by __builtin_nontemporal_load
typedef float f32x2 __attribute__((ext_vector_type(2)));

__device__ __forceinline__ float fast_exp(float v) {
    return exp2f(v * LOG2E);   // v_exp_f32
}

// Compute one TILE_B=2 tile: outputs for batch rows (brow, brow+1) from the
// transposed LDS buffer xT2[j] = {x[brow][j], x[brow+1][j]}.
__device__ __forceinline__ void compute_tile(
    const float* __restrict__ xbuf,
    const int*   __restrict__ idx,
    const float* __restrict__ w,
    const float* __restrict__ theta,
    const float* __restrict__ s_raw,
    float*       __restrict__ out,
    int brow, int t)
{
    const float2* __restrict__ xT2 = reinterpret_cast<const float2*>(xbuf);
#pragma unroll
    for (int i = 0; i < OPT; ++i) {
        const int o = t + i * NT;

        const int4*   ip = reinterpret_cast<const int4*>(idx + (size_t)o * FAN_IN);
        const float4* wp = reinterpret_cast<const float4*>(w  + (size_t)o * FAN_IN);
        const int4   i0 = ip[0], i1 = ip[1];
        const float4 w0 = wp[0], w1 = wp[1];

        float accx = 0.f, accy = 0.f;
        float2 v;
        v = xT2[i0.x]; accx = fmaf(v.x, w0.x, accx); accy = fmaf(v.y, w0.x, accy);
        v = xT2[i0.y]; accx = fmaf(v.x, w0.y, accx); accy = fmaf(v.y, w0.y, accy);
        v = xT2[i0.z]; accx = fmaf(v.x, w0.z, accx); accy = fmaf(v.y, w0.z, accy);
        v = xT2[i0.w]; accx = fmaf(v.x, w0.w, accx); accy = fmaf(v.y, w0.w, accy);
        v = xT2[i1.x]; accx = fmaf(v.x, w1.x, accx); accy = fmaf(v.y, w1.x, accy);
        v = xT2[i1.y]; accx = fmaf(v.x, w1.y, accx); accy = fmaf(v.y, w1.y, accy);
        v = xT2[i1.z]; accx = fmaf(v.x, w1.z, accx); accy = fmaf(v.y, w1.z, accy);
        v = xT2[i1.w]; accx = fmaf(v.x, w1.w, accx); accy = fmaf(v.y, w1.w, accy);

        const float th = theta[o];
        const float sr = s_raw[o];
        // softplus(sr)+1e-6, stable; log via v_log_f32: log1p(u)=log2(1+u)*ln2
        const float sp = fmaxf(sr, 0.0f) + LN2 * log2f(1.0f + fast_exp(-fabsf(sr)));
        const float s  = sp + 1e-6f;

        const float g0 = 1.0f / (1.0f + fast_exp(-s * (accx - th)));
        const float g1 = 1.0f / (1.0f + fast_exp(-s * (accy - th)));

        __builtin_nontemporal_store(g0, &out[(size_t)(brow + 0) * OUT_DIM + o]);
        __builtin_nontemporal_store(g1, &out[(size_t)(brow + 1) * OUT_DIM + o]);
    }
}

__global__ __launch_bounds__(NT, 4) void WeightedThresholdGate_53085795778563_kernel(
    const float* __restrict__ x,      // [B, IN_DIM]
    const int*   __restrict__ idx,    // [OUT_DIM, FAN_IN]
    const float* __restrict__ w,      // [OUT_DIM, FAN_IN]
    const float* __restrict__ theta,  // [OUT_DIM]
    const float* __restrict__ s_raw,  // [OUT_DIM]
    float*       __restrict__ out)    // [B, OUT_DIM]
{
    // Double-buffered transposed pair-stage: xT2[j] = {x[r0][j], x[r1][j]}.
    // 2 x 32 KiB. One block per CU processes 4 batch rows as two tiles;
    // tile-1 global loads are issued BEFORE tile-0 compute (T14 async split)
    // so their HBM latency hides under the gather phase.
    __shared__ __align__(16) float xbuf[2][IN_DIM * 2];

    const int t  = threadIdx.x;
    const int b0 = blockIdx.x * 4;

    const f32x2* __restrict__ xr0 = reinterpret_cast<const f32x2*>(x + (size_t)(b0 + 0) * IN_DIM);
    const f32x2* __restrict__ xr1 = reinterpret_cast<const f32x2*>(x + (size_t)(b0 + 1) * IN_DIM);
    const f32x2* __restrict__ xr2 = reinterpret_cast<const f32x2*>(x + (size_t)(b0 + 2) * IN_DIM);
    const f32x2* __restrict__ xr3 = reinterpret_cast<const f32x2*>(x + (size_t)(b0 + 3) * IN_DIM);

    // ---- stage tile 0 (rows b0, b0+1) ----
    f32x2 p0[STG], p1[STG];
#pragma unroll
    for (int k = 0; k < STG; ++k) {
        p0[k] = __builtin_nontemporal_load(&xr0[t + k * NT]);  // x is single-use:
        p1[k] = __builtin_nontemporal_load(&xr1[t + k * NT]);  // don't pollute L2
    }
#pragma unroll
    for (int k = 0; k < STG; ++k) {
        float4 v; v.x = p0[k].x; v.y = p1[k].x; v.z = p0[k].y; v.w = p1[k].y;
        reinterpret_cast<float4*>(xbuf[0])[t + k * NT] = v;
    }
    __syncthreads();

    // ---- issue tile-1 prefetch NOW (latency hides under tile-0 compute) ----
    f32x2 q0[STG], q1[STG];
#pragma unroll
    for (int k = 0; k < STG; ++k) {
        q0[k] = __builtin_nontemporal_load(&xr2[t + k * NT]);
        q1[k] = __builtin_nontemporal_load(&xr3[t + k * NT]);
    }
    __builtin_amdgcn_sched_barrier(0);   // pin prefetch issue ahead of compute

    // ---- compute tile 0 ----
    compute_tile(xbuf[0], idx, w, theta, s_raw, out, b0 + 0, t);

    // ---- write tile 1 into buf1 (vmcnt wait lands here, after compute) ----
#pragma unroll
    for (int k = 0; k < STG; ++k) {
        float4 v; v.x = q0[k].x; v.y = q1[k].x; v.z = q0[k].y; v.w = q1[k].y;
        reinterpret_cast<float4*>(xbuf[1])[t + k * NT] = v;
    }
    __syncthreads();

    // ---- compute tile 1 ----
    compute_tile(xbuf[1], idx, w, theta, s_raw, out, b0 + 2, t);
}

extern "C" void kernel_launch(void* const* d_in, const int* in_sizes, int n_in,
                              void* d_out, int out_size, void* d_ws, size_t ws_size,
                              hipStream_t stream) {
    const float* x     = (const float*)d_in[0];
    const int*   idx   = (const int*)  d_in[1];
    const float* w     = (const float*)d_in[2];
    const float* theta = (const float*)d_in[3];
    const float* s_raw = (const float*)d_in[4];
    float* out = (float*)d_out;

    dim3 grid(BDIM / 4);    // 256 blocks, 1 per CU, each owns 4 batch rows
    dim3 block(NT);         // 1024 threads = 16 waves = 4/SIMD
    WeightedThresholdGate_53085795778563_kernel<<<grid, block, 0, stream>>>(
        x, idx, w, theta, s_raw, out);
}

// Round 10
// 13.845 us; speedup vs baseline: 1.7567x; 1.7567x over previous
//
#include <hip/hip_runtime.h>
#include <hip/hip_fp16.h>
#include <math.h>

// Problem constants: B=1024, IN_DIM=4096, OUT_DIM=4096, FAN_IN=8
#define BDIM 1024
#define IN_DIM 4096
#define OUT_DIM 4096
#define FAN_IN 8
#define NT 1024
#define TILE_B 4
#define OPT (OUT_DIM / NT)   // 4 outputs per thread

#define LOG2E 1.442695040888963f
#define LN2   0.6931471805599453f

__device__ __forceinline__ float fast_exp(float v) {
    return exp2f(v * LOG2E);   // v_exp_f32
}

union H2U { __half2 h; unsigned int u; };

__global__ __launch_bounds__(NT, 4) void WeightedThresholdGate_53085795778563_kernel(
    const float* __restrict__ x,      // [B, IN_DIM]
    const int*   __restrict__ idx,    // [OUT_DIM, FAN_IN]
    const float* __restrict__ w,      // [OUT_DIM, FAN_IN]
    const float* __restrict__ theta,  // [OUT_DIM]
    const float* __restrict__ s_raw,  // [OUT_DIM]
    float*       __restrict__ out)    // [B, OUT_DIM]
{
    // Transposed f16 stage: xT[j] = {h(x[b0][j]),h(x[b0+1][j]) | h(x[b0+2][j]),h(x[b0+3][j])}
    // One ds_read_b64 at index j yields all 4 rows' gathered values with HALF
    // the bank traffic of the f32/b128 version (128 vs 256 bank-accesses per
    // wave gather). 32 KiB.
    __shared__ __align__(8) uint2 xT[IN_DIM];

    const int t  = threadIdx.x;
    const int b0 = blockIdx.x * TILE_B;

    const float* __restrict__ xr0 = x + (size_t)(b0 + 0) * IN_DIM;
    const float* __restrict__ xr1 = x + (size_t)(b0 + 1) * IN_DIM;
    const float* __restrict__ xr2 = x + (size_t)(b0 + 2) * IN_DIM;
    const float* __restrict__ xr3 = x + (size_t)(b0 + 3) * IN_DIM;

    // Staging: scalar global reads (each wave = 256B contiguous, coalesced);
    // v_cvt_pkrtz packs pairs; ds_write_b64 lane-contiguous (conflict-free).
#pragma unroll
    for (int k = 0; k < IN_DIM / NT; ++k) {
        const int j = t + k * NT;
        H2U lo, hi;
        lo.h = __floats2half2_rn(xr0[j], xr1[j]);   // rows 0,1
        hi.h = __floats2half2_rn(xr2[j], xr3[j]);   // rows 2,3
        xT[j] = make_uint2(lo.u, hi.u);
    }
    __syncthreads();

#pragma unroll
    for (int i = 0; i < OPT; ++i) {
        const int o = t + i * NT;

        const int4*   ip = reinterpret_cast<const int4*>(idx + (size_t)o * FAN_IN);
        const float4* wp = reinterpret_cast<const float4*>(w  + (size_t)o * FAN_IN);
        const int4   i0 = ip[0], i1 = ip[1];
        const float4 w0 = wp[0], w1 = wp[1];

        float a0 = 0.f, a1 = 0.f, a2 = 0.f, a3 = 0.f;

#define GATHER(J, WF)                                              \
        {                                                          \
            const uint2 g = xT[(J)];                               \
            H2U glo, ghi; glo.u = g.x; ghi.u = g.y;                \
            const float2 f01 = __half22float2(glo.h);              \
            const float2 f23 = __half22float2(ghi.h);              \
            a0 = fmaf(f01.x, (WF), a0);                            \
            a1 = fmaf(f01.y, (WF), a1);                            \
            a2 = fmaf(f23.x, (WF), a2);                            \
            a3 = fmaf(f23.y, (WF), a3);                            \
        }

        GATHER(i0.x, w0.x); GATHER(i0.y, w0.y);
        GATHER(i0.z, w0.z); GATHER(i0.w, w0.w);
        GATHER(i1.x, w1.x); GATHER(i1.y, w1.y);
        GATHER(i1.z, w1.z); GATHER(i1.w, w1.w);
#undef GATHER

        const float th = theta[o];
        const float sr = s_raw[o];
        // softplus(sr)+1e-6, stable; log via v_log_f32: log1p(u)=log2(1+u)*ln2
        const float sp = fmaxf(sr, 0.0f) + LN2 * log2f(1.0f + fast_exp(-fabsf(sr)));
        const float s  = sp + 1e-6f;

        const float g0 = 1.0f / (1.0f + fast_exp(-s * (a0 - th)));
        const float g1 = 1.0f / (1.0f + fast_exp(-s * (a1 - th)));
        const float g2 = 1.0f / (1.0f + fast_exp(-s * (a2 - th)));
        const float g3 = 1.0f / (1.0f + fast_exp(-s * (a3 - th)));

        // Streamed output: nontemporal, keep L2 for idx/w broadcast reuse
        __builtin_nontemporal_store(g0, &out[(size_t)(b0 + 0) * OUT_DIM + o]);
        __builtin_nontemporal_store(g1, &out[(size_t)(b0 + 1) * OUT_DIM + o]);
        __builtin_nontemporal_store(g2, &out[(size_t)(b0 + 2) * OUT_DIM + o]);
        __builtin_nontemporal_store(g3, &out[(size_t)(b0 + 3) * OUT_DIM + o]);
    }
}

extern "C" void kernel_launch(void* const* d_in, const int* in_sizes, int n_in,
                              void* d_out, int out_size, void* d_ws, size_t ws_size,
                              hipStream_t stream) {
    const float* x     = (const float*)d_in[0];
    const int*   idx   = (const int*)  d_in[1];
    const float* w     = (const float*)d_in[2];
    const float* theta = (const float*)d_in[3];
    const float* s_raw = (const float*)d_in[4];
    float* out = (float*)d_out;

    dim3 grid(BDIM / TILE_B);   // 256 blocks, 1 per CU
    dim3 block(NT);             // 1024 threads = 16 waves = 4/SIMD
    WeightedThresholdGate_53085795778563_kernel<<<grid, block, 0, stream>>>(
        x, idx, w, theta, s_raw, out);
}